// Round 1
// baseline (96.790 us; speedup 1.0000x reference)
//
#include <hip/hip_runtime.h>

#define DEV __device__ __forceinline__

typedef unsigned short u16;
typedef __attribute__((ext_vector_type(8))) __bf16 bf16x8;
typedef __attribute__((ext_vector_type(4))) float f32x4;
typedef __attribute__((ext_vector_type(8))) unsigned short u16x8;

// Problem constants: B=16, T=4096, Din=Dout=S=256
static constexpr int NB = 16;
static constexpr int NT = 4096;
static constexpr int ND = 256;
static constexpr int NM = NB * NT;   // 65536 rows
static constexpr int NCH = 64;       // chunks per batch
static constexpr int LCH = 64;       // timesteps per chunk

DEV u16 f2bf(float f) {
  unsigned u = __builtin_bit_cast(unsigned, f);
  u += 0x7fffu + ((u >> 16) & 1u);
  return (u16)(u >> 16);
}
DEV float bf2f(u16 h) {
  unsigned u = ((unsigned)h) << 16;
  return __builtin_bit_cast(float, u);
}

DEV void gl_lds16(const void* gp, void* lp) {
  __builtin_amdgcn_global_load_lds(
      (__attribute__((address_space(1))) void*)(void*)gp,
      (__attribute__((address_space(3))) void*)lp, 16, 0, 0);
}

// ---------------- prep: a = tanh(a_raw); b,c,d -> bf16 ----------------
__global__ __launch_bounds__(256) void prep_k(const float* __restrict__ a_raw,
                                              const float* __restrict__ b,
                                              const float* __restrict__ c,
                                              const float* __restrict__ d,
                                              float* __restrict__ af,
                                              u16* __restrict__ bw,
                                              u16* __restrict__ cw,
                                              u16* __restrict__ dw) {
  int i = blockIdx.x * 256 + threadIdx.x;  // grid 256 -> i < 65536
  if (i < 256) af[i] = tanhf(a_raw[i]);
  bw[i] = f2bf(b[i]);
  cw[i] = f2bf(c[i]);
  dw[i] = f2bf(d[i]);
}

// ---------------- u fp32 -> bf16, 8 elems/thread ----------------
__global__ __launch_bounds__(256) void convu_k(const float* __restrict__ u,
                                               u16* __restrict__ ub) {
  size_t i = ((size_t)blockIdx.x * 256 + threadIdx.x) * 8;
  float4 v0 = *reinterpret_cast<const float4*>(u + i);
  float4 v1 = *reinterpret_cast<const float4*>(u + i + 4);
  u16x8 o;
  o[0] = f2bf(v0.x); o[1] = f2bf(v0.y); o[2] = f2bf(v0.z); o[3] = f2bf(v0.w);
  o[4] = f2bf(v1.x); o[5] = f2bf(v1.y); o[6] = f2bf(v1.z); o[7] = f2bf(v1.w);
  *reinterpret_cast<u16x8*>(ub + i) = o;
}

// ---------------- GEMM: C[m,n] = sum_k A[m,k]*B[n,k], bf16 MFMA ----------------
// 128x128 tile, BK=64, 4 waves (2x2), each wave 64x64 (4x4 frags of 16x16x32).
// LDS tiles XOR-swizzled: logical (row, col16) lives at slot col16 ^ (row&7);
// global_load_lds writes linearly, so the global SOURCE is pre-swizzled (rule 21).
template <int NSRC, bool OUT_BF16>
__global__ __launch_bounds__(256) void gemm_k(const u16* __restrict__ A0,
                                              const u16* __restrict__ B0,
                                              const u16* __restrict__ A1,
                                              const u16* __restrict__ B1,
                                              void* __restrict__ out) {
  __shared__ u16 As[128 * 64];
  __shared__ u16 Bs[128 * 64];
  const int tid = threadIdx.x;
  const int lane = tid & 63;
  const int wid = tid >> 6;
  const int wm = wid >> 1, wn = wid & 1;
  const int row0 = blockIdx.x * 128;
  const int col0 = blockIdx.y * 128;

  const int rstg = tid >> 3;  // 0..31: row within each 32-row staging group
  const int c16 = tid & 7;    // 16B column slot

  const f32x4 zero = {0.f, 0.f, 0.f, 0.f};
  f32x4 acc[4][4];
#pragma unroll
  for (int i = 0; i < 4; ++i)
#pragma unroll
    for (int j = 0; j < 4; ++j) acc[i][j] = zero;

#pragma unroll
  for (int kt = 0; kt < 4 * NSRC; ++kt) {
    const u16* Ap = (NSRC == 2 && kt >= 4) ? A1 : A0;
    const u16* Bp = (NSRC == 2 && kt >= 4) ? B1 : B0;
    const int kb = (kt & 3) * 64;
#pragma unroll
    for (int j = 0; j < 4; ++j) {
      int row = j * 32 + rstg;
      int sc = c16 ^ (row & 7);  // inverse-swizzled source column
      gl_lds16(Ap + (size_t)(row0 + row) * 256 + kb + sc * 8,
               (char*)As + j * 4096 + wid * 1024);
      gl_lds16(Bp + (size_t)(col0 + row) * 256 + kb + sc * 8,
               (char*)Bs + j * 4096 + wid * 1024);
    }
    __syncthreads();  // compiler drains vmcnt before s_barrier
#pragma unroll
    for (int kk = 0; kk < 2; ++kk) {
      bf16x8 af[4], bfr[4];
#pragma unroll
      for (int mi = 0; mi < 4; ++mi) {
        int row = wm * 64 + mi * 16 + (lane & 15);
        int slot = (kk * 4 + (lane >> 4)) ^ (row & 7);
        af[mi] = *reinterpret_cast<const bf16x8*>(&As[row * 64 + slot * 8]);
      }
#pragma unroll
      for (int ni = 0; ni < 4; ++ni) {
        int row = wn * 64 + ni * 16 + (lane & 15);
        int slot = (kk * 4 + (lane >> 4)) ^ (row & 7);
        bfr[ni] = *reinterpret_cast<const bf16x8*>(&Bs[row * 64 + slot * 8]);
      }
#pragma unroll
      for (int mi = 0; mi < 4; ++mi)
#pragma unroll
        for (int ni = 0; ni < 4; ++ni)
          acc[mi][ni] = __builtin_amdgcn_mfma_f32_16x16x32_bf16(
              af[mi], bfr[ni], acc[mi][ni], 0, 0, 0);
    }
    __syncthreads();
  }

  // Epilogue. C/D layout (m89-verified): col = lane&15, row = (lane>>4)*4 + r
#pragma unroll
  for (int mi = 0; mi < 4; ++mi) {
    int rowb = row0 + wm * 64 + mi * 16 + (lane >> 4) * 4;
#pragma unroll
    for (int ni = 0; ni < 4; ++ni) {
      int colg = col0 + wn * 64 + ni * 16 + (lane & 15);
      f32x4 v = acc[mi][ni];
#pragma unroll
      for (int r = 0; r < 4; ++r) {
        size_t idx = (size_t)(rowb + r) * 256 + colg;
        if constexpr (OUT_BF16)
          ((u16*)out)[idx] = f2bf(v[r]);
        else
          ((float*)out)[idx] = v[r];
      }
    }
  }
}

// ---------------- scan phase 1: per-chunk carries ----------------
__global__ __launch_bounds__(256) void scan1_k(const u16* __restrict__ bu,
                                               const float* __restrict__ af,
                                               float* __restrict__ carry) {
  int blk = blockIdx.x;  // b*NCH + ch
  int b = blk >> 6, ch = blk & 63;
  int s = threadIdx.x;
  float a = af[s];
  size_t base = ((size_t)(b * NT + ch * LCH)) * 256 + s;
  float x = 0.f;
  for (int tb = 0; tb < LCH; tb += 8) {
    float vb[8];
#pragma unroll
    for (int j = 0; j < 8; ++j) vb[j] = bf2f(bu[base + (size_t)(tb + j) * 256]);
#pragma unroll
    for (int j = 0; j < 8; ++j) x = fmaf(a, x, vb[j]);
  }
  carry[(size_t)blk * 256 + s] = x;
}

// ---------------- scan phase 2: exclusive scan of carries over chunks ----------------
__global__ __launch_bounds__(256) void scan2_k(const float* __restrict__ carry,
                                               const float* __restrict__ af,
                                               float* __restrict__ initb) {
  int b = blockIdx.x;  // 16 blocks
  int s = threadIdx.x;
  float a = af[s];
  float aL = a;
#pragma unroll
  for (int i = 0; i < 6; ++i) aL *= aL;  // a^64
  float x = 0.f;
  for (int k = 0; k < NCH; ++k) {
    size_t idx = ((size_t)(b * NCH + k)) * 256 + s;
    float cv = carry[idx];
    initb[idx] = x;  // state entering chunk k
    x = fmaf(aL, x, cv);
  }
}

// ---------------- scan phase 3: replay with init, write xs bf16 in place ----------------
__global__ __launch_bounds__(256) void scan3_k(u16* __restrict__ bu,
                                               const float* __restrict__ af,
                                               const float* __restrict__ initb) {
  int blk = blockIdx.x;
  int b = blk >> 6, ch = blk & 63;
  int s = threadIdx.x;
  float a = af[s];
  float x = initb[(size_t)blk * 256 + s];
  size_t base = ((size_t)(b * NT + ch * LCH)) * 256 + s;
  for (int tb = 0; tb < LCH; tb += 8) {
    float vb[8];
#pragma unroll
    for (int j = 0; j < 8; ++j) vb[j] = bf2f(bu[base + (size_t)(tb + j) * 256]);
    u16 ob[8];
#pragma unroll
    for (int j = 0; j < 8; ++j) {
      x = fmaf(a, x, vb[j]);
      ob[j] = f2bf(x);
    }
#pragma unroll
    for (int j = 0; j < 8; ++j) bu[base + (size_t)(tb + j) * 256] = ob[j];
  }
}

extern "C" void kernel_launch(void* const* d_in, const int* in_sizes, int n_in,
                              void* d_out, int out_size, void* d_ws, size_t ws_size,
                              hipStream_t stream) {
  const float* u = (const float*)d_in[0];
  const float* a_raw = (const float*)d_in[1];
  const float* b = (const float*)d_in[2];
  const float* c = (const float*)d_in[3];
  const float* d = (const float*)d_in[4];
  float* y = (float*)d_out;
  char* ws = (char*)d_ws;

  // workspace layout (~67 MB)
  float* af = (float*)(ws);                                   // 1 KB
  u16* bw = (u16*)(ws + 4096);                                // 128 KB
  u16* cw = (u16*)(ws + 4096 + 131072);                       // 128 KB
  u16* dw = (u16*)(ws + 4096 + 2 * 131072);                   // 128 KB
  u16* ubf = (u16*)(ws + (1 << 20));                          // 32 MB
  u16* bu = (u16*)(ws + (1 << 20) + (size_t)32 * 1024 * 1024);// 32 MB (becomes xs)
  float* carry = (float*)(ws + (1 << 20) + (size_t)64 * 1024 * 1024);      // 1 MB
  float* initb = (float*)(ws + (2 << 20) + (size_t)64 * 1024 * 1024);      // 1 MB

  prep_k<<<256, 256, 0, stream>>>(a_raw, b, c, d, af, bw, cw, dw);
  convu_k<<<8192, 256, 0, stream>>>(u, ubf);
  // Bu = u @ b^T  (bf16 out)
  gemm_k<1, true><<<dim3(512, 2), 256, 0, stream>>>(ubf, bw, nullptr, nullptr, bu);
  scan1_k<<<1024, 256, 0, stream>>>(bu, af, carry);
  scan2_k<<<16, 256, 0, stream>>>(carry, af, initb);
  scan3_k<<<1024, 256, 0, stream>>>(bu, af, initb);
  // y = xs @ c^T + u @ d^T  (fp32 out)
  gemm_k<2, false><<<dim3(512, 2), 256, 0, stream>>>(bu, cw, ubf, dw, y);
}